// Round 1
// baseline (539.177 us; speedup 1.0000x reference)
//
#include <hip/hip_runtime.h>
#include <math.h>

#define N_ 8
#define C_ 8
#define F_ 257
#define T_ 1000
#define ATT_ 512
#define EPSILON_ 1.1920928955078125e-07f
#define EPS_ 1e-5f

__device__ inline float2 cmul(float2 a, float2 b){
  return make_float2(a.x*b.x - a.y*b.y, a.x*b.y + a.y*b.x);
}
__device__ inline float2 crecip(float2 a){
  float id = 1.0f/(a.x*a.x + a.y*a.y);
  return make_float2(a.x*id, -a.y*id);
}
__device__ inline float2 cdivz(float2 a, float2 b){
  float id = 1.0f/(b.x*b.x + b.y*b.y);
  return make_float2((a.x*b.x + a.y*b.y)*id, (a.y*b.x - a.x*b.y)*id);
}
__device__ inline float2 shfl2(float2 v, int src){
  return make_float2(__shfl(v.x, src, 64), __shfl(v.y, src, 64));
}

// K1a: per (n,f): max over t of |mask|, and sum of normalized mask m = mask/(max+eps)
__global__ __launch_bounds__(256) void k1a_stats(
    const float* __restrict__ mask, float* __restrict__ maxv, float* __restrict__ summ)
{
  __shared__ float smx[8][33];
  __shared__ float ssm[8][33];
  const int n = blockIdx.y;
  const int f0 = blockIdx.x*32;
  const int tx = threadIdx.x, ty = threadIdx.y;
  const int f = f0 + tx;
  float mx = 0.f, sm = 0.f;
  if (f < F_){
    for (int t = ty; t < T_; t += 8){
      float v = mask[((size_t)n*T_ + t)*F_ + f];
      mx = fmaxf(mx, fabsf(v));
      sm += v;
    }
  }
  smx[ty][tx] = mx; ssm[ty][tx] = sm;
  __syncthreads();
  if (ty == 0 && f < F_){
    #pragma unroll
    for (int k=1;k<8;++k){ mx = fmaxf(mx, smx[k][tx]); sm += ssm[k][tx]; }
    maxv[n*F_ + f] = mx;
    summ[n*F_ + f] = sm/(mx + EPSILON_);
  }
}

// K1b: normalized mask transpose (n,t,f) -> m_t (n,f,t)
__global__ __launch_bounds__(256) void k1b_transpose(
    const float* __restrict__ mask, const float* __restrict__ maxv, float* __restrict__ m_t)
{
  __shared__ float tile[32][33];
  const int n = blockIdx.z;
  const int f0 = blockIdx.y*32;
  const int t0 = blockIdx.x*32;
  const int tx = threadIdx.x, ty = threadIdx.y;
  const int f = f0 + tx;
  float inv = 0.f;
  if (f < F_) inv = 1.0f/(maxv[n*F_ + f] + EPSILON_);
  #pragma unroll
  for (int k=0;k<4;++k){
    const int tl = ty + 8*k;
    const int t = t0 + tl;
    float v = 0.f;
    if (f < F_ && t < T_) v = mask[((size_t)n*T_ + t)*F_ + f];
    tile[tl][tx] = v*inv;
  }
  __syncthreads();
  #pragma unroll
  for (int k=0;k<4;++k){
    const int fl = ty + 8*k;
    const int f2 = f0 + fl, t2 = t0 + tx;
    if (f2 < F_ && t2 < T_) m_t[((size_t)n*F_ + f2)*T_ + t2] = tile[tx][fl];
  }
}

// K2: per (n,f): Rs = (sum_t m * s_i conj(s_j))/max(sum m,eps),
//                Rn = (sum_t s_i conj(s_j) - nom_s)/max(T-sum m,eps) + EPS*I
__global__ __launch_bounds__(256) void k2_covar(
    const float* __restrict__ xre, const float* __restrict__ xim,
    const float* __restrict__ m_t, const float* __restrict__ summ,
    float2* __restrict__ Rs, float2* __restrict__ Rn)
{
  __shared__ float s_re[C_][256];
  __shared__ float s_im[C_][256];
  __shared__ float s_m[256];
  const int nf = blockIdx.x;
  const int n = nf / F_;
  const int f = nf % F_;
  const int tid = threadIdx.x;
  const int wave = tid >> 6;
  const int lane = tid & 63;
  const int r0 = wave*2;

  float t0r[8], t0i[8], s0r[8], s0i[8];
  float t1r[8], t1i[8], s1r[8], s1i[8];
  #pragma unroll
  for (int j=0;j<8;++j){ t0r[j]=t0i[j]=s0r[j]=s0i[j]=0.f; t1r[j]=t1i[j]=s1r[j]=s1i[j]=0.f; }

  const int tt = lane*4;
  for (int t0 = 0; t0 < T_; t0 += 256){
    __syncthreads();
    const bool ok = (t0 + tt + 3) < T_;
    #pragma unroll
    for (int ci=0; ci<2; ++ci){
      const int c = r0 + ci;
      const size_t base = (((size_t)n*C_ + c)*F_ + f)*T_ + t0 + tt;
      float4 vr = make_float4(0,0,0,0), vi = make_float4(0,0,0,0);
      if (ok){ vr = *(const float4*)(xre + base); vi = *(const float4*)(xim + base); }
      *(float4*)&s_re[c][tt] = vr;
      *(float4*)&s_im[c][tt] = vi;
    }
    if (wave == 0){
      float4 vm = make_float4(0,0,0,0);
      if (ok) vm = *(const float4*)(m_t + (size_t)nf*T_ + t0 + tt);
      *(float4*)&s_m[tt] = vm;
    }
    __syncthreads();
    #pragma unroll
    for (int ti=0; ti<4; ++ti){
      const int t = ti*64 + lane;
      const float mm = s_m[t];
      const float a0r = s_re[r0][t],   a0i = s_im[r0][t];
      const float a1r = s_re[r0+1][t], a1i = s_im[r0+1][t];
      #pragma unroll
      for (int j=0;j<8;++j){
        const float br = s_re[j][t], bi = s_im[j][t];
        float pr = a0r*br + a0i*bi;
        float pi = a0i*br - a0r*bi;
        t0r[j] += pr; t0i[j] += pi;
        s0r[j] += mm*pr; s0i[j] += mm*pi;
        pr = a1r*br + a1i*bi;
        pi = a1i*br - a1r*bi;
        t1r[j] += pr; t1i[j] += pi;
        s1r[j] += mm*pr; s1i[j] += mm*pi;
      }
    }
  }
  #pragma unroll
  for (int j=0;j<8;++j){
    #pragma unroll
    for (int s=1;s<64;s<<=1){
      t0r[j] += __shfl_xor(t0r[j], s, 64);
      t0i[j] += __shfl_xor(t0i[j], s, 64);
      s0r[j] += __shfl_xor(s0r[j], s, 64);
      s0i[j] += __shfl_xor(s0i[j], s, 64);
      t1r[j] += __shfl_xor(t1r[j], s, 64);
      t1i[j] += __shfl_xor(t1i[j], s, 64);
      s1r[j] += __shfl_xor(s1r[j], s, 64);
      s1i[j] += __shfl_xor(s1i[j], s, 64);
    }
  }
  if (lane == 0){
    const float sm = summ[nf];
    const float ids = 1.0f/fmaxf(sm, EPSILON_);
    const float idn = 1.0f/fmaxf((float)T_ - sm, EPSILON_);
    float2* rs0 = Rs + ((size_t)nf*8 + r0)*8;
    float2* rn0 = Rn + ((size_t)nf*8 + r0)*8;
    #pragma unroll
    for (int j=0;j<8;++j){
      rs0[j]   = make_float2(s0r[j]*ids, s0i[j]*ids);
      rn0[j]   = make_float2((t0r[j]-s0r[j])*idn + ((r0   == j)?EPS_:0.f), (t0i[j]-s0i[j])*idn);
      rs0[8+j] = make_float2(s1r[j]*ids, s1i[j]*ids);
      rn0[8+j] = make_float2((t1r[j]-s1r[j])*idn + ((r0+1 == j)?EPS_:0.f), (t1i[j]-s1i[j])*idn);
    }
  }
}

// K3: per (n,c): feat_f = |mean_offdiag Rs[n,f,c,:]|; g = gvec . tanh(proj_w @ feat + proj_b) + gvec_b
__global__ __launch_bounds__(256) void k3_gate(
    const float2* __restrict__ Rs, const float* __restrict__ proj_w,
    const float* __restrict__ proj_b, const float* __restrict__ gvec_w,
    const float* __restrict__ gvec_b, float* __restrict__ g)
{
  __shared__ float feat[F_ + 3];
  __shared__ float plds[ATT_];
  __shared__ float wsum[4];
  const int nc = blockIdx.x;
  const int n = nc >> 3, c = nc & 7;
  const int tid = threadIdx.x;
  for (int f = tid; f < F_; f += 256){
    const float2* row = Rs + (((size_t)n*F_ + f)*8 + c)*8;
    float sr = 0.f, si = 0.f;
    #pragma unroll
    for (int j=0;j<8;++j){ float2 v = row[j]; sr += v.x; si += v.y; }
    float2 d = row[c];
    sr = (sr - d.x)*(1.0f/7.0f);
    si = (si - d.y)*(1.0f/7.0f);
    feat[f] = sqrtf(sr*sr + si*si);
  }
  __syncthreads();
  const int wave = tid >> 6, lane = tid & 63;
  for (int a = wave; a < ATT_; a += 4){
    float acc = 0.f;
    const float* wr = proj_w + (size_t)a*F_;
    for (int fi = lane; fi < F_; fi += 64) acc += feat[fi]*wr[fi];
    #pragma unroll
    for (int s=1;s<64;s<<=1) acc += __shfl_xor(acc, s, 64);
    if (lane == 0) plds[a] = tanhf(acc + proj_b[a]);
  }
  __syncthreads();
  float v = plds[tid]*gvec_w[tid] + plds[tid+256]*gvec_w[tid+256];
  #pragma unroll
  for (int s=1;s<64;s<<=1) v += __shfl_xor(v, s, 64);
  if (lane == 0) wsum[wave] = v;
  __syncthreads();
  if (tid == 0) g[nc] = wsum[0]+wsum[1]+wsum[2]+wsum[3] + gvec_b[0];
}

// K4: one wave per (n,f): softmax(u), invert Rn (8x8 complex, lane=(i,j)), w = Rn^-1 (Rs u) / (tr(Rn^-1 Rs)+EPS)
__global__ __launch_bounds__(256) void k4_solve(
    const float2* __restrict__ Rs, const float2* __restrict__ Rn,
    const float* __restrict__ g, float2* __restrict__ w_ws)
{
  const int tid = threadIdx.x;
  const int wid = blockIdx.x*4 + (tid >> 6);
  const int lane = tid & 63;
  const int ii = lane >> 3, jj = lane & 7;
  const int n = wid / F_;
  float2 A = Rn[(size_t)wid*64 + lane];
  float2 R = Rs[(size_t)wid*64 + lane];
  // softmax over the 8 channel gates -> u_{jj}
  float gv = g[n*C_ + jj];
  float mx = gv;
  #pragma unroll
  for (int s=1;s<8;s<<=1) mx = fmaxf(mx, __shfl_xor(mx, s, 64));
  float e = expf(gv - mx);
  float es = e;
  #pragma unroll
  for (int s=1;s<8;s<<=1) es += __shfl_xor(es, s, 64);
  const float u = e / es;
  // in-place Gauss-Jordan inversion (no pivoting; Hermitian PD)
  #pragma unroll
  for (int k=0;k<8;++k){
    float2 piv    = shfl2(A, k*9);
    float2 oldAkj = shfl2(A, k*8 + jj);
    float2 dum    = shfl2(A, ii*8 + k);
    float2 pinv = crecip(piv);
    float2 newk = (jj==k) ? pinv : cmul(oldAkj, pinv);
    if (ii == k){
      A = newk;
    } else {
      float2 b = (jj==k) ? make_float2(0.f,0.f) : A;
      float2 t = cmul(newk, dum);
      A = make_float2(b.x - t.x, b.y - t.y);
    }
  }
  // v_i = sum_j Rs[i][j]*u_j  (u real), row-group butterfly
  float2 v = make_float2(R.x*u, R.y*u);
  #pragma unroll
  for (int s=1;s<8;s<<=1){ v.x += __shfl_xor(v.x, s, 64); v.y += __shfl_xor(v.y, s, 64); }
  // tr = sum_{i,j} A[i][j]*Rs[j][i]
  float2 Rt = shfl2(R, jj*8 + ii);
  float2 tp = cmul(A, Rt);
  #pragma unroll
  for (int s=1;s<64;s<<=1){ tp.x += __shfl_xor(tp.x, s, 64); tp.y += __shfl_xor(tp.y, s, 64); }
  tp.x += EPS_;
  // w_i = (sum_j A[i][j]*v_j)/tr
  float2 vj = shfl2(v, jj*8);
  float2 q = cmul(A, vj);
  #pragma unroll
  for (int s=1;s<8;s<<=1){ q.x += __shfl_xor(q.x, s, 64); q.y += __shfl_xor(q.y, s, 64); }
  float2 wv = cdivz(q, tp);
  if (jj == 0) w_ws[(size_t)wid*8 + ii] = wv;
}

// K5: beam[n,t,f] = sum_c conj(w[n,f,c]) * x[n,c,f,t]; output (n,t,f,2) via LDS transpose
__global__ __launch_bounds__(256) void k5_beam(
    const float* __restrict__ xre, const float* __restrict__ xim,
    const float2* __restrict__ w_ws, float* __restrict__ out)
{
  __shared__ float b_re[32][129];
  __shared__ float b_im[32][129];
  __shared__ float2 w_l[32][8];
  const int n = blockIdx.z;
  const int f0 = blockIdx.y*32;
  const int t0 = blockIdx.x*128;
  const int tid = threadIdx.x;
  {
    const int fl = tid >> 3, c = tid & 7;
    const int f = f0 + fl;
    w_l[fl][c] = (f < F_) ? w_ws[((size_t)n*F_ + f)*8 + c] : make_float2(0.f,0.f);
  }
  __syncthreads();
  const int tq = (tid & 31)*4;
  const int fg = tid >> 5;
  const int t = t0 + tq;
  const bool tok = (t + 3) < T_;
  #pragma unroll
  for (int fi=0; fi<4; ++fi){
    const int fl = fg + fi*8;
    const int f = f0 + fl;
    float4 ar = make_float4(0,0,0,0), ai = make_float4(0,0,0,0);
    if (f < F_ && tok){
      #pragma unroll
      for (int c=0;c<8;++c){
        const size_t base = (((size_t)n*C_ + c)*F_ + f)*T_ + t;
        const float4 xr = *(const float4*)(xre + base);
        const float4 xi = *(const float4*)(xim + base);
        const float2 wv = w_l[fl][c];
        ar.x += wv.x*xr.x + wv.y*xi.x;  ai.x += wv.x*xi.x - wv.y*xr.x;
        ar.y += wv.x*xr.y + wv.y*xi.y;  ai.y += wv.x*xi.y - wv.y*xr.y;
        ar.z += wv.x*xr.z + wv.y*xi.z;  ai.z += wv.x*xi.z - wv.y*xr.z;
        ar.w += wv.x*xr.w + wv.y*xi.w;  ai.w += wv.x*xi.w - wv.y*xr.w;
      }
    }
    b_re[fl][tq+0]=ar.x; b_re[fl][tq+1]=ar.y; b_re[fl][tq+2]=ar.z; b_re[fl][tq+3]=ar.w;
    b_im[fl][tq+0]=ai.x; b_im[fl][tq+1]=ai.y; b_im[fl][tq+2]=ai.z; b_im[fl][tq+3]=ai.w;
  }
  __syncthreads();
  const int fl2 = tid & 31;
  const int tp = tid >> 5;
  const int f2 = f0 + fl2;
  if (f2 < F_){
    #pragma unroll
    for (int k=0;k<16;++k){
      const int tl = tp + k*8;
      const int t2 = t0 + tl;
      if (t2 < T_){
        float2 v = make_float2(b_re[fl2][tl], b_im[fl2][tl]);
        *(float2*)(out + (((size_t)n*T_ + t2)*F_ + f2)*2) = v;
      }
    }
  }
}

extern "C" void kernel_launch(void* const* d_in, const int* in_sizes, int n_in,
                              void* d_out, int out_size, void* d_ws, size_t ws_size,
                              hipStream_t stream)
{
  const float* mask   = (const float*)d_in[0];
  const float* xre    = (const float*)d_in[1];
  const float* xim    = (const float*)d_in[2];
  const float* proj_w = (const float*)d_in[3];
  const float* proj_b = (const float*)d_in[4];
  const float* gvec_w = (const float*)d_in[5];
  const float* gvec_b = (const float*)d_in[6];
  float* out = (float*)d_out;
  char* ws = (char*)d_ws;

  size_t o = 0;
  auto alloc = [&](size_t bytes){ size_t r = o; o += (bytes + 255) & ~(size_t)255; return r; };
  float*  m_t  = (float*) (ws + alloc((size_t)N_*F_*T_*4));
  float*  maxv = (float*) (ws + alloc((size_t)N_*F_*4));
  float*  summ = (float*) (ws + alloc((size_t)N_*F_*4));
  float2* Rs   = (float2*)(ws + alloc((size_t)N_*F_*64*8));
  float2* Rn   = (float2*)(ws + alloc((size_t)N_*F_*64*8));
  float*  g    = (float*) (ws + alloc((size_t)N_*C_*4));
  float2* w_ws = (float2*)(ws + alloc((size_t)N_*F_*C_*8));

  k1a_stats   <<<dim3(9, N_),     dim3(32,8), 0, stream>>>(mask, maxv, summ);
  k1b_transpose<<<dim3(32, 9, N_), dim3(32,8), 0, stream>>>(mask, maxv, m_t);
  k2_covar    <<<dim3(N_*F_),     dim3(256),  0, stream>>>(xre, xim, m_t, summ, Rs, Rn);
  k3_gate     <<<dim3(N_*C_),     dim3(256),  0, stream>>>(Rs, proj_w, proj_b, gvec_w, gvec_b, g);
  k4_solve    <<<dim3(N_*F_/4),   dim3(256),  0, stream>>>(Rs, Rn, g, w_ws);
  k5_beam     <<<dim3(8, 9, N_),  dim3(256),  0, stream>>>(xre, xim, w_ws, out);
}

// Round 2
// 371.556 us; speedup vs baseline: 1.4511x; 1.4511x over previous
//
#include <hip/hip_runtime.h>
#include <math.h>

#define N_ 8
#define C_ 8
#define F_ 257
#define T_ 1000
#define ATT_ 512
#define EPSILON_ 1.1920928955078125e-07f
#define EPS_ 1e-5f

__device__ inline float2 cmul(float2 a, float2 b){
  return make_float2(a.x*b.x - a.y*b.y, a.x*b.y + a.y*b.x);
}
__device__ inline float2 crecip(float2 a){
  float id = 1.0f/(a.x*a.x + a.y*a.y);
  return make_float2(a.x*id, -a.y*id);
}
__device__ inline float2 cdivz(float2 a, float2 b){
  float id = 1.0f/(b.x*b.x + b.y*b.y);
  return make_float2((a.x*b.x + a.y*b.y)*id, (a.y*b.x - a.x*b.y)*id);
}
__device__ inline float2 shfl2(float2 v, int src){
  return make_float2(__shfl(v.x, src, 64), __shfl(v.y, src, 64));
}

// K1a: per (n,f): max over t of |mask|, and sum of normalized mask m = mask/(max+eps)
__global__ __launch_bounds__(256) void k1a_stats(
    const float* __restrict__ mask, float* __restrict__ maxv, float* __restrict__ summ)
{
  __shared__ float smx[8][33];
  __shared__ float ssm[8][33];
  const int n = blockIdx.y;
  const int f0 = blockIdx.x*32;
  const int tx = threadIdx.x, ty = threadIdx.y;
  const int f = f0 + tx;
  float mx = 0.f, sm = 0.f;
  if (f < F_){
    for (int t = ty; t < T_; t += 8){
      float v = mask[((size_t)n*T_ + t)*F_ + f];
      mx = fmaxf(mx, fabsf(v));
      sm += v;
    }
  }
  smx[ty][tx] = mx; ssm[ty][tx] = sm;
  __syncthreads();
  if (ty == 0 && f < F_){
    #pragma unroll
    for (int k=1;k<8;++k){ mx = fmaxf(mx, smx[k][tx]); sm += ssm[k][tx]; }
    maxv[n*F_ + f] = mx;
    summ[n*F_ + f] = sm/(mx + EPSILON_);
  }
}

// K1b: normalized mask transpose (n,t,f) -> m_t (n,f,t)
__global__ __launch_bounds__(256) void k1b_transpose(
    const float* __restrict__ mask, const float* __restrict__ maxv, float* __restrict__ m_t)
{
  __shared__ float tile[32][33];
  const int n = blockIdx.z;
  const int f0 = blockIdx.y*32;
  const int t0 = blockIdx.x*32;
  const int tx = threadIdx.x, ty = threadIdx.y;
  const int f = f0 + tx;
  float inv = 0.f;
  if (f < F_) inv = 1.0f/(maxv[n*F_ + f] + EPSILON_);
  #pragma unroll
  for (int k=0;k<4;++k){
    const int tl = ty + 8*k;
    const int t = t0 + tl;
    float v = 0.f;
    if (f < F_ && t < T_) v = mask[((size_t)n*T_ + t)*F_ + f];
    tile[tl][tx] = v*inv;
  }
  __syncthreads();
  #pragma unroll
  for (int k=0;k<4;++k){
    const int fl = ty + 8*k;
    const int f2 = f0 + fl, t2 = t0 + tx;
    if (f2 < F_ && t2 < T_) m_t[((size_t)n*F_ + f2)*T_ + t2] = tile[tx][fl];
  }
}

// K2: per (n,f): Rs = (sum_t m * s_i conj(s_j))/max(sum m,eps),
//                Rn = (sum_t s_i conj(s_j) - nom_s)/max(T-sum m,eps) + EPS*I
__global__ __launch_bounds__(256) void k2_covar(
    const float* __restrict__ xre, const float* __restrict__ xim,
    const float* __restrict__ m_t, const float* __restrict__ summ,
    float2* __restrict__ Rs, float2* __restrict__ Rn)
{
  __shared__ float s_re[C_][256];
  __shared__ float s_im[C_][256];
  __shared__ float s_m[256];
  const int nf = blockIdx.x;
  const int n = nf / F_;
  const int f = nf % F_;
  const int tid = threadIdx.x;
  const int wave = tid >> 6;
  const int lane = tid & 63;
  const int r0 = wave*2;

  float t0r[8], t0i[8], s0r[8], s0i[8];
  float t1r[8], t1i[8], s1r[8], s1i[8];
  #pragma unroll
  for (int j=0;j<8;++j){ t0r[j]=t0i[j]=s0r[j]=s0i[j]=0.f; t1r[j]=t1i[j]=s1r[j]=s1i[j]=0.f; }

  const int tt = lane*4;
  for (int t0 = 0; t0 < T_; t0 += 256){
    __syncthreads();
    const bool ok = (t0 + tt + 3) < T_;
    #pragma unroll
    for (int ci=0; ci<2; ++ci){
      const int c = r0 + ci;
      const size_t base = (((size_t)n*C_ + c)*F_ + f)*T_ + t0 + tt;
      float4 vr = make_float4(0,0,0,0), vi = make_float4(0,0,0,0);
      if (ok){ vr = *(const float4*)(xre + base); vi = *(const float4*)(xim + base); }
      *(float4*)&s_re[c][tt] = vr;
      *(float4*)&s_im[c][tt] = vi;
    }
    if (wave == 0){
      float4 vm = make_float4(0,0,0,0);
      if (ok) vm = *(const float4*)(m_t + (size_t)nf*T_ + t0 + tt);
      *(float4*)&s_m[tt] = vm;
    }
    __syncthreads();
    #pragma unroll
    for (int ti=0; ti<4; ++ti){
      const int t = ti*64 + lane;
      const float mm = s_m[t];
      const float a0r = s_re[r0][t],   a0i = s_im[r0][t];
      const float a1r = s_re[r0+1][t], a1i = s_im[r0+1][t];
      #pragma unroll
      for (int j=0;j<8;++j){
        const float br = s_re[j][t], bi = s_im[j][t];
        float pr = a0r*br + a0i*bi;
        float pi = a0i*br - a0r*bi;
        t0r[j] += pr; t0i[j] += pi;
        s0r[j] += mm*pr; s0i[j] += mm*pi;
        pr = a1r*br + a1i*bi;
        pi = a1i*br - a1r*bi;
        t1r[j] += pr; t1i[j] += pi;
        s1r[j] += mm*pr; s1i[j] += mm*pi;
      }
    }
  }
  #pragma unroll
  for (int j=0;j<8;++j){
    #pragma unroll
    for (int s=1;s<64;s<<=1){
      t0r[j] += __shfl_xor(t0r[j], s, 64);
      t0i[j] += __shfl_xor(t0i[j], s, 64);
      s0r[j] += __shfl_xor(s0r[j], s, 64);
      s0i[j] += __shfl_xor(s0i[j], s, 64);
      t1r[j] += __shfl_xor(t1r[j], s, 64);
      t1i[j] += __shfl_xor(t1i[j], s, 64);
      s1r[j] += __shfl_xor(s1r[j], s, 64);
      s1i[j] += __shfl_xor(s1i[j], s, 64);
    }
  }
  if (lane == 0){
    const float sm = summ[nf];
    const float ids = 1.0f/fmaxf(sm, EPSILON_);
    const float idn = 1.0f/fmaxf((float)T_ - sm, EPSILON_);
    float2* rs0 = Rs + ((size_t)nf*8 + r0)*8;
    float2* rn0 = Rn + ((size_t)nf*8 + r0)*8;
    #pragma unroll
    for (int j=0;j<8;++j){
      rs0[j]   = make_float2(s0r[j]*ids, s0i[j]*ids);
      rn0[j]   = make_float2((t0r[j]-s0r[j])*idn + ((r0   == j)?EPS_:0.f), (t0i[j]-s0i[j])*idn);
      rs0[8+j] = make_float2(s1r[j]*ids, s1i[j]*ids);
      rn0[8+j] = make_float2((t1r[j]-s1r[j])*idn + ((r0+1 == j)?EPS_:0.f), (t1i[j]-s1i[j])*idn);
    }
  }
}

// K3a: feat[nc][f] = |mean offdiag of Rs row c| ; also zero the gate accumulators g[64]
__global__ __launch_bounds__(256) void k3a_feat(
    const float2* __restrict__ Rs, float* __restrict__ feat, float* __restrict__ g)
{
  const int nc = blockIdx.x;
  const int n = nc >> 3, c = nc & 7;
  const int tid = threadIdx.x;
  if (nc == 0 && tid < N_*C_) g[tid] = 0.f;
  for (int f = tid; f < F_; f += 256){
    const float2* row = Rs + (((size_t)n*F_ + f)*8 + c)*8;
    float sr = 0.f, si = 0.f;
    #pragma unroll
    for (int j=0;j<8;++j){ float2 v = row[j]; sr += v.x; si += v.y; }
    float2 d = row[c];
    sr = (sr - d.x)*(1.0f/7.0f);
    si = (si - d.y)*(1.0f/7.0f);
    feat[(size_t)nc*F_ + f] = sqrtf(sr*sr + si*si);
  }
}

// K3b: g[nc] += sum_a tanh(feat[nc,:] . proj_w[a,:] + proj_b[a]) * gvec_w[a]
// grid.x = chunk (32 chunks of 16 atts), grid.y = nc; 4 waves x 4 atts per wave.
__global__ __launch_bounds__(256) void k3b_proj(
    const float* __restrict__ feat, const float* __restrict__ proj_w,
    const float* __restrict__ proj_b, const float* __restrict__ gvec_w,
    float* __restrict__ g)
{
  const int nc = blockIdx.y;
  const int tid = threadIdx.x;
  const int wave = tid >> 6, lane = tid & 63;
  const int a0 = blockIdx.x*16 + wave*4;
  float acc0 = 0.f, acc1 = 0.f, acc2 = 0.f, acc3 = 0.f;
  const float* fr = feat + (size_t)nc*F_;
  const float* w0 = proj_w + (size_t)(a0+0)*F_;
  const float* w1 = proj_w + (size_t)(a0+1)*F_;
  const float* w2 = proj_w + (size_t)(a0+2)*F_;
  const float* w3 = proj_w + (size_t)(a0+3)*F_;
  for (int fi = lane; fi < F_; fi += 64){
    const float fv = fr[fi];
    acc0 += fv*w0[fi];
    acc1 += fv*w1[fi];
    acc2 += fv*w2[fi];
    acc3 += fv*w3[fi];
  }
  #pragma unroll
  for (int s=1;s<64;s<<=1){
    acc0 += __shfl_xor(acc0, s, 64);
    acc1 += __shfl_xor(acc1, s, 64);
    acc2 += __shfl_xor(acc2, s, 64);
    acc3 += __shfl_xor(acc3, s, 64);
  }
  if (lane == 0){
    float v = tanhf(acc0 + proj_b[a0+0])*gvec_w[a0+0]
            + tanhf(acc1 + proj_b[a0+1])*gvec_w[a0+1]
            + tanhf(acc2 + proj_b[a0+2])*gvec_w[a0+2]
            + tanhf(acc3 + proj_b[a0+3])*gvec_w[a0+3];
    atomicAdd(&g[nc], v);
  }
}

// K4: one wave per (n,f): softmax(u), invert Rn (8x8 complex, lane=(i,j)), w = Rn^-1 (Rs u) / (tr(Rn^-1 Rs)+EPS)
// (gvec_b is omitted from g: softmax is shift-invariant.)
__global__ __launch_bounds__(256) void k4_solve(
    const float2* __restrict__ Rs, const float2* __restrict__ Rn,
    const float* __restrict__ g, float2* __restrict__ w_ws)
{
  const int tid = threadIdx.x;
  const int wid = blockIdx.x*4 + (tid >> 6);
  const int lane = tid & 63;
  const int ii = lane >> 3, jj = lane & 7;
  const int n = wid / F_;
  float2 A = Rn[(size_t)wid*64 + lane];
  float2 R = Rs[(size_t)wid*64 + lane];
  // softmax over the 8 channel gates -> u_{jj}
  float gv = g[n*C_ + jj];
  float mx = gv;
  #pragma unroll
  for (int s=1;s<8;s<<=1) mx = fmaxf(mx, __shfl_xor(mx, s, 64));
  float e = expf(gv - mx);
  float es = e;
  #pragma unroll
  for (int s=1;s<8;s<<=1) es += __shfl_xor(es, s, 64);
  const float u = e / es;
  // in-place Gauss-Jordan inversion (no pivoting; Hermitian PD)
  #pragma unroll
  for (int k=0;k<8;++k){
    float2 piv    = shfl2(A, k*9);
    float2 oldAkj = shfl2(A, k*8 + jj);
    float2 dum    = shfl2(A, ii*8 + k);
    float2 pinv = crecip(piv);
    float2 newk = (jj==k) ? pinv : cmul(oldAkj, pinv);
    if (ii == k){
      A = newk;
    } else {
      float2 b = (jj==k) ? make_float2(0.f,0.f) : A;
      float2 t = cmul(newk, dum);
      A = make_float2(b.x - t.x, b.y - t.y);
    }
  }
  // v_i = sum_j Rs[i][j]*u_j  (u real), row-group butterfly
  float2 v = make_float2(R.x*u, R.y*u);
  #pragma unroll
  for (int s=1;s<8;s<<=1){ v.x += __shfl_xor(v.x, s, 64); v.y += __shfl_xor(v.y, s, 64); }
  // tr = sum_{i,j} A[i][j]*Rs[j][i]
  float2 Rt = shfl2(R, jj*8 + ii);
  float2 tp = cmul(A, Rt);
  #pragma unroll
  for (int s=1;s<64;s<<=1){ tp.x += __shfl_xor(tp.x, s, 64); tp.y += __shfl_xor(tp.y, s, 64); }
  tp.x += EPS_;
  // w_i = (sum_j A[i][j]*v_j)/tr
  float2 vj = shfl2(v, jj*8);
  float2 q = cmul(A, vj);
  #pragma unroll
  for (int s=1;s<8;s<<=1){ q.x += __shfl_xor(q.x, s, 64); q.y += __shfl_xor(q.y, s, 64); }
  float2 wv = cdivz(q, tp);
  if (jj == 0) w_ws[(size_t)wid*8 + ii] = wv;
}

// K5: beam[n,t,f] = sum_c conj(w[n,f,c]) * x[n,c,f,t]; output (n,t,f,2) via LDS transpose
__global__ __launch_bounds__(256) void k5_beam(
    const float* __restrict__ xre, const float* __restrict__ xim,
    const float2* __restrict__ w_ws, float* __restrict__ out)
{
  __shared__ float b_re[32][129];
  __shared__ float b_im[32][129];
  __shared__ float2 w_l[32][8];
  const int n = blockIdx.z;
  const int f0 = blockIdx.y*32;
  const int t0 = blockIdx.x*128;
  const int tid = threadIdx.x;
  {
    const int fl = tid >> 3, c = tid & 7;
    const int f = f0 + fl;
    w_l[fl][c] = (f < F_) ? w_ws[((size_t)n*F_ + f)*8 + c] : make_float2(0.f,0.f);
  }
  __syncthreads();
  const int tq = (tid & 31)*4;
  const int fg = tid >> 5;
  const int t = t0 + tq;
  const bool tok = (t + 3) < T_;
  #pragma unroll
  for (int fi=0; fi<4; ++fi){
    const int fl = fg + fi*8;
    const int f = f0 + fl;
    float4 ar = make_float4(0,0,0,0), ai = make_float4(0,0,0,0);
    if (f < F_ && tok){
      #pragma unroll
      for (int c=0;c<8;++c){
        const size_t base = (((size_t)n*C_ + c)*F_ + f)*T_ + t;
        const float4 xr = *(const float4*)(xre + base);
        const float4 xi = *(const float4*)(xim + base);
        const float2 wv = w_l[fl][c];
        ar.x += wv.x*xr.x + wv.y*xi.x;  ai.x += wv.x*xi.x - wv.y*xr.x;
        ar.y += wv.x*xr.y + wv.y*xi.y;  ai.y += wv.x*xi.y - wv.y*xr.y;
        ar.z += wv.x*xr.z + wv.y*xi.z;  ai.z += wv.x*xi.z - wv.y*xr.z;
        ar.w += wv.x*xr.w + wv.y*xi.w;  ai.w += wv.x*xi.w - wv.y*xr.w;
      }
    }
    b_re[fl][tq+0]=ar.x; b_re[fl][tq+1]=ar.y; b_re[fl][tq+2]=ar.z; b_re[fl][tq+3]=ar.w;
    b_im[fl][tq+0]=ai.x; b_im[fl][tq+1]=ai.y; b_im[fl][tq+2]=ai.z; b_im[fl][tq+3]=ai.w;
  }
  __syncthreads();
  const int fl2 = tid & 31;
  const int tp = tid >> 5;
  const int f2 = f0 + fl2;
  if (f2 < F_){
    #pragma unroll
    for (int k=0;k<16;++k){
      const int tl = tp + k*8;
      const int t2 = t0 + tl;
      if (t2 < T_){
        float2 v = make_float2(b_re[fl2][tl], b_im[fl2][tl]);
        *(float2*)(out + (((size_t)n*T_ + t2)*F_ + f2)*2) = v;
      }
    }
  }
}

extern "C" void kernel_launch(void* const* d_in, const int* in_sizes, int n_in,
                              void* d_out, int out_size, void* d_ws, size_t ws_size,
                              hipStream_t stream)
{
  const float* mask   = (const float*)d_in[0];
  const float* xre    = (const float*)d_in[1];
  const float* xim    = (const float*)d_in[2];
  const float* proj_w = (const float*)d_in[3];
  const float* proj_b = (const float*)d_in[4];
  const float* gvec_w = (const float*)d_in[5];
  const float* gvec_b = (const float*)d_in[6];
  (void)gvec_b;
  float* out = (float*)d_out;
  char* ws = (char*)d_ws;

  size_t o = 0;
  auto alloc = [&](size_t bytes){ size_t r = o; o += (bytes + 255) & ~(size_t)255; return r; };
  float*  m_t  = (float*) (ws + alloc((size_t)N_*F_*T_*4));
  float*  maxv = (float*) (ws + alloc((size_t)N_*F_*4));
  float*  summ = (float*) (ws + alloc((size_t)N_*F_*4));
  float2* Rs   = (float2*)(ws + alloc((size_t)N_*F_*64*8));
  float2* Rn   = (float2*)(ws + alloc((size_t)N_*F_*64*8));
  float*  g    = (float*) (ws + alloc((size_t)N_*C_*4));
  float*  feat = (float*) (ws + alloc((size_t)N_*C_*F_*4));
  float2* w_ws = (float2*)(ws + alloc((size_t)N_*F_*C_*8));

  k1a_stats    <<<dim3(9, N_),      dim3(32,8), 0, stream>>>(mask, maxv, summ);
  k1b_transpose<<<dim3(32, 9, N_),  dim3(32,8), 0, stream>>>(mask, maxv, m_t);
  k2_covar     <<<dim3(N_*F_),      dim3(256),  0, stream>>>(xre, xim, m_t, summ, Rs, Rn);
  k3a_feat     <<<dim3(N_*C_),      dim3(256),  0, stream>>>(Rs, feat, g);
  k3b_proj     <<<dim3(32, N_*C_),  dim3(256),  0, stream>>>(feat, proj_w, proj_b, gvec_w, g);
  k4_solve     <<<dim3(N_*F_/4),    dim3(256),  0, stream>>>(Rs, Rn, g, w_ws);
  k5_beam      <<<dim3(8, 9, N_),   dim3(256),  0, stream>>>(xre, xim, w_ws, out);
}